// Round 16
// baseline (59.521 us; speedup 1.0000x reference)
//
#include <hip/hip_runtime.h>
#include <hip/hip_bf16.h>
#include <math.h>

#define BB  4
#define TT  8192
#define DD  64
#define PP  8
#define CC  32            // chunk length along t
#define NCH (TT/CC)       // 256 chunks
#define AGG_STRIDE 130    // 64 cos-d + 64 sin-d + cosK + sinK
#define QSTR 68           // pass1 padded Q row stride (floats)

#define EPSV 1e-3f
#define KPI4 0.78539816339744830962f

typedef __attribute__((ext_vector_type(8))) short short8;   // 8 bf16
typedef __attribute__((ext_vector_type(4))) float f32x4;

__device__ __forceinline__ float bf2f(unsigned short h) {
  return __uint_as_float(((unsigned)h) << 16);
}
__device__ __forceinline__ unsigned short f2bf(float f) {   // RNE
  unsigned u = __float_as_uint(f);
  u += 0x7fffu + ((u >> 16) & 1u);
  return (unsigned short)(u >> 16);
}
__device__ __forceinline__ float fast_tanh(float x) {
  float e = __expf(2.f * x);
  return 1.f - 2.f * __builtin_amdgcn_rcpf(e + 1.f);
}
__device__ __forceinline__ float rlane(float v, int lane) {
  return __uint_as_float(__builtin_amdgcn_readlane(__float_as_uint(v), lane));
}

// ---- Pass 1: per-(b,chunk) aggregates; blocks 0..63 also build WvT hi/lo ----
// Wave w owns p = 2w (lanes 0-31) and 2w+1 (lanes 32-63); trig in registers.
__global__ __launch_bounds__(256) void k_pass1(const float* __restrict__ q,
                                               const float* __restrict__ Wk,
                                               const float* __restrict__ Wv,
                                               float* __restrict__ agg,
                                               unsigned short* __restrict__ WvTh,
                                               unsigned short* __restrict__ WvTl) {
  const int blk = blockIdx.x;
  const int c = blk & (NCH - 1);
  const int b = blk >> 8;

  __shared__ float SH[64 * QSTR];           // Qs (32 rows); reused for Wv transpose
  __shared__ float Wks[PP * DD];

  const int tid = threadIdx.x;
  const int w = tid >> 6, l = tid & 63;
  const float* qb = q + ((size_t)b * TT + (size_t)c * CC) * DD;
  for (int g = tid; g < CC * DD; g += 256) SH[(g >> 6) * QSTR + (g & 63)] = qb[g];
  for (int g = tid; g < PP * DD; g += 256) Wks[g] = Wk[g];
  __syncthreads();

  float ckR, skR;
  {  // k-dots + trig + shfl-reduce sums: thread = (t, p) with p = tid>>5 = 2w+sub
    const int t = tid & 31, p = tid >> 5;
    float dk = 0.f;
    const float4* qr = (const float4*)&SH[t * QSTR];
    const float4* wr = (const float4*)&Wks[p * DD];
#pragma unroll
    for (int j = 0; j < 16; ++j) {
      float4 qv = qr[j], wv = wr[j];
      dk = fmaf(qv.x, wv.x, dk); dk = fmaf(qv.y, wv.y, dk);
      dk = fmaf(qv.z, wv.z, dk); dk = fmaf(qv.w, wv.w, dk);
    }
    float ang = fast_tanh(dk) * KPI4;
    ckR = __cosf(ang); skR = __sinf(ang);
    float rc = ckR, rs = skR;
#pragma unroll
    for (int d = 16; d >= 1; d >>= 1) {
      rc += __shfl_xor(rc, d, 32);
      rs += __shfl_xor(rs, d, 32);
    }
    if (t == 0)
      *(float2*)(agg + (size_t)((b * PP + p) * NCH + c) * AGG_STRIDE + 128) =
          make_float2(rc, rs);
  }

  {  // d-space aggregates: wave w covers p0=2w (lanes 0-31 trig), p1=2w+1.
    const int i = l;
    const int p0 = 2 * w, p1 = 2 * w + 1;
    float c0 = 0, s0 = 0, c1 = 0, s1 = 0;
#pragma unroll
    for (int t = 0; t < CC; ++t) {
      float qv = SH[t * QSTR + i];
      c0 = fmaf(rlane(ckR, t), qv, c0);
      s0 = fmaf(rlane(skR, t), qv, s0);
      c1 = fmaf(rlane(ckR, t + 32), qv, c1);
      s1 = fmaf(rlane(skR, t + 32), qv, s1);
    }
    float* a0 = agg + (size_t)((b * PP + p0) * NCH + c) * AGG_STRIDE;
    float* a1 = agg + (size_t)((b * PP + p1) * NCH + c) * AGG_STRIDE;
    a0[i] = c0; a0[64 + i] = s0;
    a1[i] = c1; a1[64 + i] = s1;
  }

  // WvT build with k-column permutation: col = (p&1)*256 + (p>>1)*64 + i.
  if (blk < 64) {
    __syncthreads();
    const int k0 = blk * 8;
#pragma unroll
    for (int r = 0; r < 2; ++r) {
      int idx = tid + r * 256;
      int kk = idx >> 6, o = idx & 63;                   // coalesced over o
      SH[o * QSTR + kk] = Wv[(size_t)(k0 + kk) * DD + o];
    }
    __syncthreads();
#pragma unroll
    for (int r = 0; r < 2; ++r) {
      int idx = tid + r * 256;
      int o = idx >> 3, kk = idx & 7;
      int k = k0 + kk;
      int p = k >> 6, i = k & 63;
      int col = ((p & 1) << 8) + ((p >> 1) << 6) + i;
      float wv = SH[o * QSTR + kk];
      unsigned short hi = f2bf(wv);
      WvTh[(size_t)o * 512 + col] = hi;
      WvTl[(size_t)o * 512 + col] = f2bf(wv - bf2f(hi));
    }
  }
}

// ---- Pass 2: hierarchical exclusive scan over 256 chunks, 4-way segmented ----
__global__ __launch_bounds__(576) void k_pass2(float* __restrict__ agg) {
  const int bp = blockIdx.x;
  const int tid = threadIdx.x;
  __shared__ float totals[4][132];

  const bool act = tid < 520;
  int seg = 0, m = 0;
  float* base = agg;
  float vals[64];
  if (act) {
    seg = tid / 130;
    m = tid - seg * 130;
    base = agg + (size_t)bp * NCH * AGG_STRIDE + m;
    float run = 0.f;
#pragma unroll
    for (int u = 0; u < 64; ++u) vals[u] = base[(size_t)(seg * 64 + u) * AGG_STRIDE];
#pragma unroll
    for (int u = 0; u < 64; ++u) run += vals[u];
    totals[seg][m] = run;
  }
  __syncthreads();
  if (act) {
    float r2 = 0.f;
    for (int s = 0; s < seg; ++s) r2 += totals[s][m];
#pragma unroll
    for (int u = 0; u < 64; ++u) {
      float v = vals[u];
      base[(size_t)(seg * 64 + u) * AGG_STRIDE] = r2;
      r2 += v;
    }
  }
}

// ---- Pass 3: LDS = 40960 B exactly (4 blocks/CU); reg-trig; 5-bit swizzle ----
__global__ __launch_bounds__(256, 3) void k_pass3(
    const float* __restrict__ q, const float* __restrict__ Wq,
    const float* __restrict__ Wk, const float* __restrict__ Wo,
    const float* __restrict__ pref,
    const unsigned short* __restrict__ WvTh,
    const unsigned short* __restrict__ WvTl,
    float* __restrict__ out) {
  const int blk = blockIdx.x;
  const int c = blk & (NCH - 1);
  const int b = blk >> 8;

  __shared__ float Qs[CC * 64];                            // 8 KB, stride 64
  __shared__ __align__(16) short Zh[CC * 256];             // 16 KB (swizzled)
  __shared__ __align__(16) short Zl[CC * 256];             // 16 KB

  const int tid = threadIdx.x;
  const int w = tid >> 6, l = tid & 63;
  const int lm = l & 15, lg = l >> 4;
  const int oc = w << 4;                                   // wave's 16 o-cols

  // Prefetch h=0 B-fragments (WvT) into registers.
  short8 bhf[8], blf[8];
  {
    const unsigned short* ph_ = WvTh + (size_t)(oc + lm) * 512 + lg * 8;
    const unsigned short* pl_ = WvTl + (size_t)(oc + lm) * 512 + lg * 8;
#pragma unroll
    for (int kk = 0; kk < 8; ++kk) {
      bhf[kk] = *(const short8*)(ph_ + kk * 32);
      blf[kk] = *(const short8*)(pl_ + kk * 32);
    }
  }

  const float* qb = q + ((size_t)b * TT + (size_t)c * CC) * DD;
  for (int g = tid; g < CC * DD; g += 256) Qs[g] = qb[g];  // linear, conflict-free

  // Phase A: dots from GLOBAL (q rows L1-hot from staging; Wq/Wk broadcast)
  // + trig + in-segment shfl scan — all in registers. Wave w: p=2w | 2w+1.
  float ckR, skR, alR, beR;
  {
    const int t = tid & 31, p = tid >> 5;
    float dq = 0.f, dk = 0.f;
    const float4* qr  = (const float4*)(qb + t * DD);
    const float4* wqr = (const float4*)(Wq + p * DD);
    const float4* wkr = (const float4*)(Wk + p * DD);
#pragma unroll
    for (int j = 0; j < 16; ++j) {
      float4 qv = qr[j], w0 = wqr[j], w1 = wkr[j];
      dq = fmaf(qv.x, w0.x, dq); dq = fmaf(qv.y, w0.y, dq);
      dq = fmaf(qv.z, w0.z, dq); dq = fmaf(qv.w, w0.w, dq);
      dk = fmaf(qv.x, w1.x, dk); dk = fmaf(qv.y, w1.y, dk);
      dk = fmaf(qv.z, w1.z, dk); dk = fmaf(qv.w, w1.w, dk);
    }
    float ang = fast_tanh(dq) * KPI4;
    float cq = __cosf(ang), sq = __sinf(ang);
    ang = fast_tanh(dk) * KPI4;
    ckR = __cosf(ang); skR = __sinf(ang);

    float rc = ckR, rs = skR;
#pragma unroll
    for (int d = 1; d < 32; d <<= 1) {
      float tc = __shfl_up(rc, (unsigned)d, 32);
      float ts = __shfl_up(rs, (unsigned)d, 32);
      if (t >= d) { rc += tc; rs += ts; }
    }
    const float* pr = pref + (size_t)((b * PP + p) * NCH + c) * AGG_STRIDE;
    rc += pr[128]; rs += pr[129];
    float den = fmaf(cq, rc, fmaf(sq, rs, EPSV));
    float ws = Wo[p] * __builtin_amdgcn_rcpf(den);
    alR = ws * cq; beR = ws * sq;
  }
  __syncthreads();   // Qs staged (phase B reads other lanes' staging)

  char* zbaseH = (char*)Zh;
  char* zbaseL = (char*)Zl;
  f32x4 acc0 = {0, 0, 0, 0}, acc1 = {0, 0, 0, 0};

#pragma unroll
  for (int h = 0; h < 2; ++h) {
    {  // Phase B(h): wave w handles p = 2w+h; trig via readlane(., t+h*32).
      const int p = 2 * w + h;
      const float* prC = pref + (size_t)((b * PP + p) * NCH + c) * AGG_STRIDE;
      float Ac = prC[l], As = prC[64 + l];
      const int kb = (w * 64 + l) * 2;     // byte offset in 512-B Z row
      const int ls = h << 5;
#pragma unroll 8
      for (int t = 0; t < CC; ++t) {
        float qv = Qs[t * 64 + l];          // stride-64: 2-way aliasing (free)
        float ck = rlane(ckR, t + ls), sk = rlane(skR, t + ls);
        float al = rlane(alR, t + ls), be = rlane(beR, t + ls);
        Ac = fmaf(ck, qv, Ac);
        As = fmaf(sk, qv, As);
        float z = fmaf(al, Ac, be * As);
        unsigned u = __float_as_uint(z);
        unsigned r = u + 0x7fffu + ((u >> 16) & 1u);
        const int ad = (t << 9) + (kb ^ (t << 4));   // 5-bit slot swizzle
        *(short*)(zbaseH + ad) = (short)(r >> 16);
        float lo = z - __uint_as_float(r & 0xffff0000u);
        *(short*)(zbaseL + ad) = (short)(__float_as_uint(lo) >> 16);
      }
    }
    __syncthreads();
    // Phase C(h): pure ds_read + MFMA (B-frags already in registers).
#pragma unroll
    for (int kk = 0; kk < 8; ++kk) {
      const int base = kk * 64 + lg * 16;
      const int rb0 = (lm << 9) + (base ^ (lm << 4));
      const int rb1 = ((16 + lm) << 9) + (base ^ ((16 + lm) << 4));
      short8 ah0 = *(const short8*)(zbaseH + rb0);
      short8 al0 = *(const short8*)(zbaseL + rb0);
      short8 ah1 = *(const short8*)(zbaseH + rb1);
      short8 al1 = *(const short8*)(zbaseL + rb1);
      acc0 = __builtin_amdgcn_mfma_f32_16x16x32_bf16(ah0, bhf[kk], acc0, 0, 0, 0);
      acc1 = __builtin_amdgcn_mfma_f32_16x16x32_bf16(ah1, bhf[kk], acc1, 0, 0, 0);
      acc0 = __builtin_amdgcn_mfma_f32_16x16x32_bf16(al0, bhf[kk], acc0, 0, 0, 0);
      acc1 = __builtin_amdgcn_mfma_f32_16x16x32_bf16(al1, bhf[kk], acc1, 0, 0, 0);
      acc0 = __builtin_amdgcn_mfma_f32_16x16x32_bf16(ah0, blf[kk], acc0, 0, 0, 0);
      acc1 = __builtin_amdgcn_mfma_f32_16x16x32_bf16(ah1, blf[kk], acc1, 0, 0, 0);
    }
    if (h == 0) {  // prefetch h=1 B-fragments; latency hides under B(1)
      const unsigned short* ph_ = WvTh + (size_t)(oc + lm) * 512 + 256 + lg * 8;
      const unsigned short* pl_ = WvTl + (size_t)(oc + lm) * 512 + 256 + lg * 8;
#pragma unroll
      for (int kk = 0; kk < 8; ++kk) {
        bhf[kk] = *(const short8*)(ph_ + kk * 32);
        blf[kk] = *(const short8*)(pl_ + kk * 32);
      }
      __syncthreads();   // Z consumed; B(1) may overwrite
    }
  }

  // Epilogue: C/D layout col=lane&15 (o), row=(lane>>4)*4+reg (t)  [m89]
  {
    float* ob = out + ((size_t)b * TT + (size_t)c * CC + lg * 4) * DD + oc + lm;
#pragma unroll
    for (int r = 0; r < 4; ++r) {
      ob[r * DD] = acc0[r];
      ob[(16 + r) * DD] = acc1[r];
    }
  }
}

extern "C" void kernel_launch(void* const* d_in, const int* in_sizes, int n_in,
                              void* d_out, int out_size, void* d_ws, size_t ws_size,
                              hipStream_t stream) {
  const float* q  = (const float*)d_in[0];
  const float* Wq = (const float*)d_in[1];
  const float* Wk = (const float*)d_in[2];
  const float* Wv = (const float*)d_in[3];
  const float* Wo = (const float*)d_in[4];
  float* out = (float*)d_out;
  float* agg = (float*)d_ws;  // BB*PP*NCH*130 floats = 4,259,840 B
  unsigned short* WvTh = (unsigned short*)(agg + (size_t)BB * PP * NCH * AGG_STRIDE);
  unsigned short* WvTl = WvTh + (size_t)512 * 64;   // +64 KB each

  k_pass1<<<BB * NCH, 256, 0, stream>>>(q, Wk, Wv, agg, WvTh, WvTl);
  k_pass2<<<BB * PP, 576, 0, stream>>>(agg);
  k_pass3<<<BB * NCH, 256, 0, stream>>>(q, Wq, Wk, Wo, agg, WvTh, WvTl, out);
}

// Round 17
// 50.195 us; speedup vs baseline: 1.1858x; 1.1858x over previous
//
#include <hip/hip_runtime.h>
#include <hip/hip_bf16.h>
#include <math.h>

#define BB  4
#define TT  8192
#define DD  64
#define PP  8
#define CC  32            // chunk length along t
#define NCH (TT/CC)       // 256 chunks
#define AGG_STRIDE 130    // 64 cos-d + 64 sin-d + cosK + sinK
#define QSTR 68           // pass1 padded Q row stride (floats)

#define EPSV 1e-3f
#define KPI4 0.78539816339744830962f

typedef __attribute__((ext_vector_type(8))) short short8;   // 8 bf16
typedef __attribute__((ext_vector_type(4))) float f32x4;

__device__ __forceinline__ float bf2f(unsigned short h) {
  return __uint_as_float(((unsigned)h) << 16);
}
__device__ __forceinline__ unsigned short f2bf(float f) {   // RNE
  unsigned u = __float_as_uint(f);
  u += 0x7fffu + ((u >> 16) & 1u);
  return (unsigned short)(u >> 16);
}
__device__ __forceinline__ float fast_tanh(float x) {
  float e = __expf(2.f * x);
  return 1.f - 2.f * __builtin_amdgcn_rcpf(e + 1.f);
}
__device__ __forceinline__ float rlane(float v, int lane) {
  return __uint_as_float(__builtin_amdgcn_readlane(__float_as_uint(v), lane));
}
// Qs swizzle (float index): row t, col c -> (t<<6) + (c ^ ((t&15)<<2))
__device__ __forceinline__ int qswz(int t, int c) {
  return (t << 6) + (c ^ ((t & 15) << 2));
}

// ---- Pass 1: per-(b,chunk) aggregates; blocks 0..63 also build WvT hi/lo ----
// Wave w owns p = 2w (lanes 0-31) and 2w+1 (lanes 32-63); trig in registers.
__global__ __launch_bounds__(256) void k_pass1(const float* __restrict__ q,
                                               const float* __restrict__ Wk,
                                               const float* __restrict__ Wv,
                                               float* __restrict__ agg,
                                               unsigned short* __restrict__ WvTh,
                                               unsigned short* __restrict__ WvTl) {
  const int blk = blockIdx.x;
  const int c = blk & (NCH - 1);
  const int b = blk >> 8;

  __shared__ float SH[64 * QSTR];           // Qs (32 rows); reused for Wv transpose
  __shared__ float Wks[PP * DD];

  const int tid = threadIdx.x;
  const int w = tid >> 6, l = tid & 63;
  const float* qb = q + ((size_t)b * TT + (size_t)c * CC) * DD;
  for (int g = tid; g < CC * DD; g += 256) SH[(g >> 6) * QSTR + (g & 63)] = qb[g];
  for (int g = tid; g < PP * DD; g += 256) Wks[g] = Wk[g];
  __syncthreads();

  float ckR, skR;
  {  // k-dots + trig + shfl-reduce sums: thread = (t, p) with p = tid>>5 = 2w+sub
    const int t = tid & 31, p = tid >> 5;
    float dk = 0.f;
    const float4* qr = (const float4*)&SH[t * QSTR];
    const float4* wr = (const float4*)&Wks[p * DD];
#pragma unroll
    for (int j = 0; j < 16; ++j) {
      float4 qv = qr[j], wv = wr[j];
      dk = fmaf(qv.x, wv.x, dk); dk = fmaf(qv.y, wv.y, dk);
      dk = fmaf(qv.z, wv.z, dk); dk = fmaf(qv.w, wv.w, dk);
    }
    float ang = fast_tanh(dk) * KPI4;
    ckR = __cosf(ang); skR = __sinf(ang);
    float rc = ckR, rs = skR;
#pragma unroll
    for (int d = 16; d >= 1; d >>= 1) {
      rc += __shfl_xor(rc, d, 32);
      rs += __shfl_xor(rs, d, 32);
    }
    if (t == 0)
      *(float2*)(agg + (size_t)((b * PP + p) * NCH + c) * AGG_STRIDE + 128) =
          make_float2(rc, rs);
  }

  {  // d-space aggregates: wave w covers p0=2w (lanes 0-31 trig), p1=2w+1.
    const int i = l;
    const int p0 = 2 * w, p1 = 2 * w + 1;
    float c0 = 0, s0 = 0, c1 = 0, s1 = 0;
#pragma unroll
    for (int t = 0; t < CC; ++t) {
      float qv = SH[t * QSTR + i];
      c0 = fmaf(rlane(ckR, t), qv, c0);
      s0 = fmaf(rlane(skR, t), qv, s0);
      c1 = fmaf(rlane(ckR, t + 32), qv, c1);
      s1 = fmaf(rlane(skR, t + 32), qv, s1);
    }
    float* a0 = agg + (size_t)((b * PP + p0) * NCH + c) * AGG_STRIDE;
    float* a1 = agg + (size_t)((b * PP + p1) * NCH + c) * AGG_STRIDE;
    a0[i] = c0; a0[64 + i] = s0;
    a1[i] = c1; a1[64 + i] = s1;
  }

  // WvT build with k-column permutation: col = (p&1)*256 + (p>>1)*64 + i.
  if (blk < 64) {
    __syncthreads();
    const int k0 = blk * 8;
#pragma unroll
    for (int r = 0; r < 2; ++r) {
      int idx = tid + r * 256;
      int kk = idx >> 6, o = idx & 63;                   // coalesced over o
      SH[o * QSTR + kk] = Wv[(size_t)(k0 + kk) * DD + o];
    }
    __syncthreads();
#pragma unroll
    for (int r = 0; r < 2; ++r) {
      int idx = tid + r * 256;
      int o = idx >> 3, kk = idx & 7;
      int k = k0 + kk;
      int p = k >> 6, i = k & 63;
      int col = ((p & 1) << 8) + ((p >> 1) << 6) + i;
      float wv = SH[o * QSTR + kk];
      unsigned short hi = f2bf(wv);
      WvTh[(size_t)o * 512 + col] = hi;
      WvTl[(size_t)o * 512 + col] = f2bf(wv - bf2f(hi));
    }
  }
}

// ---- Pass 2: hierarchical exclusive scan over 256 chunks, 4-way segmented ----
__global__ __launch_bounds__(576) void k_pass2(float* __restrict__ agg) {
  const int bp = blockIdx.x;
  const int tid = threadIdx.x;
  __shared__ float totals[4][132];

  const bool act = tid < 520;
  int seg = 0, m = 0;
  float* base = agg;
  float vals[64];
  if (act) {
    seg = tid / 130;
    m = tid - seg * 130;
    base = agg + (size_t)bp * NCH * AGG_STRIDE + m;
    float run = 0.f;
#pragma unroll
    for (int u = 0; u < 64; ++u) vals[u] = base[(size_t)(seg * 64 + u) * AGG_STRIDE];
#pragma unroll
    for (int u = 0; u < 64; ++u) run += vals[u];
    totals[seg][m] = run;
  }
  __syncthreads();
  if (act) {
    float r2 = 0.f;
    for (int s = 0; s < seg; ++s) r2 += totals[s][m];
#pragma unroll
    for (int u = 0; u < 64; ++u) {
      float v = vals[u];
      base[(size_t)(seg * 64 + u) * AGG_STRIDE] = r2;
      r2 += v;
    }
  }
}

// ---- Pass 3: swizzled Qs (8 KB) + Z (32 KB) = 40960 B -> 4 blocks/CU ----
__global__ __launch_bounds__(256, 3) void k_pass3(
    const float* __restrict__ q, const float* __restrict__ Wq,
    const float* __restrict__ Wk, const float* __restrict__ Wo,
    const float* __restrict__ pref,
    const unsigned short* __restrict__ WvTh,
    const unsigned short* __restrict__ WvTl,
    float* __restrict__ out) {
  const int blk = blockIdx.x;
  const int c = blk & (NCH - 1);
  const int b = blk >> 8;

  __shared__ float Qs[CC * 64];                            // 8 KB, XOR-swizzled
  __shared__ __align__(16) short Zh[CC * 256];             // 16 KB (swizzled)
  __shared__ __align__(16) short Zl[CC * 256];             // 16 KB

  const int tid = threadIdx.x;
  const int w = tid >> 6, l = tid & 63;
  const int lm = l & 15, lg = l >> 4;
  const int oc = w << 4;                                   // wave's 16 o-cols

  // Prefetch h=0 B-fragments (WvT) into registers.
  short8 bhf[8], blf[8];
  {
    const unsigned short* ph_ = WvTh + (size_t)(oc + lm) * 512 + lg * 8;
    const unsigned short* pl_ = WvTl + (size_t)(oc + lm) * 512 + lg * 8;
#pragma unroll
    for (int kk = 0; kk < 8; ++kk) {
      bhf[kk] = *(const short8*)(ph_ + kk * 32);
      blf[kk] = *(const short8*)(pl_ + kk * 32);
    }
  }

  const float* qb = q + ((size_t)b * TT + (size_t)c * CC) * DD;
  for (int g = tid; g < CC * DD; g += 256)
    Qs[qswz(g >> 6, g & 63)] = qb[g];                      // 2-way max: free
  __syncthreads();

  // Phase A: dots (q from LDS swizzled; Wq/Wk wave-uniform global broadcast)
  // + trig + in-segment shfl scan — all in registers. Wave w: p=2w | 2w+1.
  float ckR, skR, alR, beR;
  {
    const int t = tid & 31, p = tid >> 5;
    float dq = 0.f, dk = 0.f;
    const float4* wqr = (const float4*)(Wq + p * DD);
    const float4* wkr = (const float4*)(Wk + p * DD);
#pragma unroll
    for (int j = 0; j < 16; ++j) {
      float4 qv = *(const float4*)&Qs[qswz(t, 4 * j)];     // 4-way (same as padded)
      float4 w0 = wqr[j], w1 = wkr[j];
      dq = fmaf(qv.x, w0.x, dq); dq = fmaf(qv.y, w0.y, dq);
      dq = fmaf(qv.z, w0.z, dq); dq = fmaf(qv.w, w0.w, dq);
      dk = fmaf(qv.x, w1.x, dk); dk = fmaf(qv.y, w1.y, dk);
      dk = fmaf(qv.z, w1.z, dk); dk = fmaf(qv.w, w1.w, dk);
    }
    float ang = fast_tanh(dq) * KPI4;
    float cq = __cosf(ang), sq = __sinf(ang);
    ang = fast_tanh(dk) * KPI4;
    ckR = __cosf(ang); skR = __sinf(ang);

    float rc = ckR, rs = skR;
#pragma unroll
    for (int d = 1; d < 32; d <<= 1) {
      float tc = __shfl_up(rc, (unsigned)d, 32);
      float ts = __shfl_up(rs, (unsigned)d, 32);
      if (t >= d) { rc += tc; rs += ts; }
    }
    const float* pr = pref + (size_t)((b * PP + p) * NCH + c) * AGG_STRIDE;
    rc += pr[128]; rs += pr[129];
    float den = fmaf(cq, rc, fmaf(sq, rs, EPSV));
    float ws = Wo[p] * __builtin_amdgcn_rcpf(den);
    alR = ws * cq; beR = ws * sq;
  }

  char* zbaseH = (char*)Zh;
  char* zbaseL = (char*)Zl;
  f32x4 acc0 = {0, 0, 0, 0}, acc1 = {0, 0, 0, 0};

#pragma unroll
  for (int h = 0; h < 2; ++h) {
    {  // Phase B(h): wave w handles p = 2w+h; trig via readlane(., t+h*32).
      const int p = 2 * w + h;
      const float* prC = pref + (size_t)((b * PP + p) * NCH + c) * AGG_STRIDE;
      float Ac = prC[l], As = prC[64 + l];
      const int kb = (w * 64 + l) * 2;     // byte offset in 512-B Z row
      const int ls = h << 5;
#pragma unroll 8
      for (int t = 0; t < CC; ++t) {
        float qv = Qs[qswz(t, l)];          // 2-way max: free
        float ck = rlane(ckR, t + ls), sk = rlane(skR, t + ls);
        float al = rlane(alR, t + ls), be = rlane(beR, t + ls);
        Ac = fmaf(ck, qv, Ac);
        As = fmaf(sk, qv, As);
        float z = fmaf(al, Ac, be * As);
        unsigned u = __float_as_uint(z);
        unsigned r = u + 0x7fffu + ((u >> 16) & 1u);
        const int ad = (t << 9) + (kb ^ (t << 4));   // 5-bit slot swizzle
        *(short*)(zbaseH + ad) = (short)(r >> 16);
        float lo = z - __uint_as_float(r & 0xffff0000u);
        *(short*)(zbaseL + ad) = (short)(__float_as_uint(lo) >> 16);
      }
    }
    __syncthreads();
    // Phase C(h): pure ds_read + MFMA (B-frags already in registers).
#pragma unroll
    for (int kk = 0; kk < 8; ++kk) {
      const int base = kk * 64 + lg * 16;
      const int rb0 = (lm << 9) + (base ^ (lm << 4));
      const int rb1 = ((16 + lm) << 9) + (base ^ ((16 + lm) << 4));
      short8 ah0 = *(const short8*)(zbaseH + rb0);
      short8 al0 = *(const short8*)(zbaseL + rb0);
      short8 ah1 = *(const short8*)(zbaseH + rb1);
      short8 al1 = *(const short8*)(zbaseL + rb1);
      acc0 = __builtin_amdgcn_mfma_f32_16x16x32_bf16(ah0, bhf[kk], acc0, 0, 0, 0);
      acc1 = __builtin_amdgcn_mfma_f32_16x16x32_bf16(ah1, bhf[kk], acc1, 0, 0, 0);
      acc0 = __builtin_amdgcn_mfma_f32_16x16x32_bf16(al0, bhf[kk], acc0, 0, 0, 0);
      acc1 = __builtin_amdgcn_mfma_f32_16x16x32_bf16(al1, bhf[kk], acc1, 0, 0, 0);
      acc0 = __builtin_amdgcn_mfma_f32_16x16x32_bf16(ah0, blf[kk], acc0, 0, 0, 0);
      acc1 = __builtin_amdgcn_mfma_f32_16x16x32_bf16(ah1, blf[kk], acc1, 0, 0, 0);
    }
    if (h == 0) {  // prefetch h=1 B-fragments; latency hides under B(1)
      const unsigned short* ph_ = WvTh + (size_t)(oc + lm) * 512 + 256 + lg * 8;
      const unsigned short* pl_ = WvTl + (size_t)(oc + lm) * 512 + 256 + lg * 8;
#pragma unroll
      for (int kk = 0; kk < 8; ++kk) {
        bhf[kk] = *(const short8*)(ph_ + kk * 32);
        blf[kk] = *(const short8*)(pl_ + kk * 32);
      }
      __syncthreads();   // Z consumed; B(1) may overwrite
    }
  }

  // Epilogue: C/D layout col=lane&15 (o), row=(lane>>4)*4+reg (t)  [m89]
  {
    float* ob = out + ((size_t)b * TT + (size_t)c * CC + lg * 4) * DD + oc + lm;
#pragma unroll
    for (int r = 0; r < 4; ++r) {
      ob[r * DD] = acc0[r];
      ob[(16 + r) * DD] = acc1[r];
    }
  }
}

extern "C" void kernel_launch(void* const* d_in, const int* in_sizes, int n_in,
                              void* d_out, int out_size, void* d_ws, size_t ws_size,
                              hipStream_t stream) {
  const float* q  = (const float*)d_in[0];
  const float* Wq = (const float*)d_in[1];
  const float* Wk = (const float*)d_in[2];
  const float* Wv = (const float*)d_in[3];
  const float* Wo = (const float*)d_in[4];
  float* out = (float*)d_out;
  float* agg = (float*)d_ws;  // BB*PP*NCH*130 floats = 4,259,840 B
  unsigned short* WvTh = (unsigned short*)(agg + (size_t)BB * PP * NCH * AGG_STRIDE);
  unsigned short* WvTl = WvTh + (size_t)512 * 64;   // +64 KB each

  k_pass1<<<BB * NCH, 256, 0, stream>>>(q, Wk, Wv, agg, WvTh, WvTl);
  k_pass2<<<BB * PP, 576, 0, stream>>>(agg);
  k_pass3<<<BB * NCH, 256, 0, stream>>>(q, Wq, Wk, Wo, agg, WvTh, WvTl, out);
}

// Round 18
// 44.751 us; speedup vs baseline: 1.3300x; 1.1217x over previous
//
#include <hip/hip_runtime.h>
#include <hip/hip_bf16.h>
#include <math.h>

#define BB  4
#define TT  8192
#define DD  64
#define PP  8
#define CC  32            // chunk length along t
#define NCH (TT/CC)       // 256 chunks
#define AGG_STRIDE 130    // 64 cos-d + 64 sin-d + cosK + sinK
#define QSTR 68           // padded Q row stride (floats)

#define EPSV 1e-3f
#define KPI4 0.78539816339744830962f

typedef __attribute__((ext_vector_type(8))) short short8;   // 8 bf16
typedef __attribute__((ext_vector_type(4))) float f32x4;

__device__ __forceinline__ float bf2f(unsigned short h) {
  return __uint_as_float(((unsigned)h) << 16);
}
__device__ __forceinline__ unsigned short f2bf(float f) {   // RNE
  unsigned u = __float_as_uint(f);
  u += 0x7fffu + ((u >> 16) & 1u);
  return (unsigned short)(u >> 16);
}
__device__ __forceinline__ float fast_tanh(float x) {
  float e = __expf(2.f * x);
  return 1.f - 2.f * __builtin_amdgcn_rcpf(e + 1.f);
}

// ---- Pass 1: per-(b,chunk) aggregates; blocks 0..63 also build WvT hi/lo ----
__global__ __launch_bounds__(256) void k_pass1(const float* __restrict__ q,
                                               const float* __restrict__ Wk,
                                               const float* __restrict__ Wv,
                                               float* __restrict__ agg,
                                               unsigned short* __restrict__ WvTh,
                                               unsigned short* __restrict__ WvTl) {
  const int blk = blockIdx.x;
  const int c = blk & (NCH - 1);
  const int b = blk >> 8;

  __shared__ float SH[64 * QSTR];           // Qs (32 rows); reused for Wv transpose
  __shared__ float Wks[PP * DD];
  __shared__ float2 kts[PP * 32];           // {ck, sk}

  const int tid = threadIdx.x;
  const float* qb = q + ((size_t)b * TT + (size_t)c * CC) * DD;
  for (int g = tid; g < CC * DD; g += 256) SH[(g >> 6) * QSTR + (g & 63)] = qb[g];
  for (int g = tid; g < PP * DD; g += 256) Wks[g] = Wk[g];
  __syncthreads();

  {  // k-dots + trig + shfl-reduce sums: thread = (t, p)
    const int t = tid & 31, p = tid >> 5;
    float dk = 0.f;
    const float4* qr = (const float4*)&SH[t * QSTR];
    const float4* wr = (const float4*)&Wks[p * DD];
#pragma unroll
    for (int j = 0; j < 16; ++j) {
      float4 qv = qr[j], wv = wr[j];
      dk = fmaf(qv.x, wv.x, dk); dk = fmaf(qv.y, wv.y, dk);
      dk = fmaf(qv.z, wv.z, dk); dk = fmaf(qv.w, wv.w, dk);
    }
    float ang = fast_tanh(dk) * KPI4;
    float ck = __cosf(ang), sk = __sinf(ang);
    kts[p * 32 + t] = make_float2(ck, sk);
    float rc = ck, rs = sk;
#pragma unroll
    for (int d = 16; d >= 1; d >>= 1) {
      rc += __shfl_xor(rc, d, 32);
      rs += __shfl_xor(rs, d, 32);
    }
    if (t == 0)
      *(float2*)(agg + (size_t)((b * PP + p) * NCH + c) * AGG_STRIDE + 128) =
          make_float2(rc, rs);
  }
  __syncthreads();

  {  // d-space aggregates: thread = (i, p-pair)
    const int i = tid & 63, pq = tid >> 6;
    const int p0 = pq, p1 = pq + 4;
    float c0 = 0, s0 = 0, c1 = 0, s1 = 0;
#pragma unroll
    for (int t = 0; t < CC; ++t) {
      float qv = SH[t * QSTR + i];
      float2 k0v = kts[p0 * 32 + t];
      float2 k1v = kts[p1 * 32 + t];
      c0 = fmaf(k0v.x, qv, c0);
      s0 = fmaf(k0v.y, qv, s0);
      c1 = fmaf(k1v.x, qv, c1);
      s1 = fmaf(k1v.y, qv, s1);
    }
    float* a0 = agg + (size_t)((b * PP + p0) * NCH + c) * AGG_STRIDE;
    float* a1 = agg + (size_t)((b * PP + p1) * NCH + c) * AGG_STRIDE;
    a0[i] = c0; a0[64 + i] = s0;
    a1[i] = c1; a1[64 + i] = s1;
  }

  // Wv transpose + double-bf16 split: blocks 0..63, one 8-k tile each.
  if (blk < 64) {
    __syncthreads();
    const int k0 = blk * 8;
#pragma unroll
    for (int r = 0; r < 2; ++r) {
      int idx = tid + r * 256;
      int kk = idx >> 6, o = idx & 63;                   // coalesced over o
      SH[o * QSTR + kk] = Wv[(size_t)(k0 + kk) * DD + o];
    }
    __syncthreads();
#pragma unroll
    for (int r = 0; r < 2; ++r) {
      int idx = tid + r * 256;
      int o = idx >> 3, kk = idx & 7;                    // coalesced over kk
      float wv = SH[o * QSTR + kk];
      unsigned short hi = f2bf(wv);
      WvTh[(size_t)o * 512 + k0 + kk] = hi;
      WvTl[(size_t)o * 512 + k0 + kk] = f2bf(wv - bf2f(hi));
    }
  }
}

// ---- Pass 2: hierarchical exclusive scan over 256 chunks, 4-way segmented ----
__global__ __launch_bounds__(576) void k_pass2(float* __restrict__ agg) {
  const int bp = blockIdx.x;
  const int tid = threadIdx.x;
  __shared__ float totals[4][132];

  const bool act = tid < 520;
  int seg = 0, m = 0;
  float* base = agg;
  float vals[64];
  if (act) {
    seg = tid / 130;
    m = tid - seg * 130;
    base = agg + (size_t)bp * NCH * AGG_STRIDE + m;
    float run = 0.f;
#pragma unroll
    for (int u = 0; u < 64; ++u) vals[u] = base[(size_t)(seg * 64 + u) * AGG_STRIDE];
#pragma unroll
    for (int u = 0; u < 64; ++u) run += vals[u];
    totals[seg][m] = run;
  }
  __syncthreads();
  if (act) {
    float r2 = 0.f;
    for (int s = 0; s < seg; ++s) r2 += totals[s][m];
#pragma unroll
    for (int u = 0; u < 64; ++u) {
      float v = vals[u];
      base[(size_t)(seg * 64 + u) * AGG_STRIDE] = r2;
      r2 += v;
    }
  }
}

// ---- Pass 3: trig+scan -> Z(hi/lo bf16, 5-bit swizzle) -> 3-term MFMA GEMM ----
__global__ __launch_bounds__(256, 3) void k_pass3(
    const float* __restrict__ q, const float* __restrict__ Wq,
    const float* __restrict__ Wk, const float* __restrict__ Wo,
    const float* __restrict__ pref,
    const unsigned short* __restrict__ WvTh,
    const unsigned short* __restrict__ WvTl,
    float* __restrict__ out) {
  const int blk = blockIdx.x;
  const int c = blk & (NCH - 1);
  const int b = blk >> 8;

  __shared__ float Qs[CC * QSTR];                          // 8.7 KB
  __shared__ float Wqs[PP * DD], Wks[PP * DD];             // 4 KB
  __shared__ float2 kts[PP * 32];                          // {ck,sk} 2 KB
  __shared__ float2 abt[PP * 32];                          // {al,be} 2 KB
  __shared__ __align__(16) short Zh[CC * 256];             // 16 KB (swizzled)
  __shared__ __align__(16) short Zl[CC * 256];             // 16 KB

  const int tid = threadIdx.x;
  const int w = tid >> 6, l = tid & 63;
  const int lm = l & 15, lg = l >> 4;
  const int oc = w << 4;                                   // wave's 16 o-cols

  // Prefetch h=0 B-fragments (WvT) into registers — independent of all LDS.
  short8 bhf[8], blf[8];
  {
    const unsigned short* ph_ = WvTh + (size_t)(oc + lm) * 512 + lg * 8;
    const unsigned short* pl_ = WvTl + (size_t)(oc + lm) * 512 + lg * 8;
#pragma unroll
    for (int kk = 0; kk < 8; ++kk) {
      bhf[kk] = *(const short8*)(ph_ + kk * 32);
      blf[kk] = *(const short8*)(pl_ + kk * 32);
    }
  }

  const float* qb = q + ((size_t)b * TT + (size_t)c * CC) * DD;
  for (int g = tid; g < CC * DD; g += 256) Qs[(g >> 6) * QSTR + (g & 63)] = qb[g];
  for (int g = tid; g < PP * DD; g += 256) { Wqs[g] = Wq[g]; Wks[g] = Wk[g]; }
  __syncthreads();

  // Phase A: dots + trig + in-segment shfl scan -> packed {ck,sk},{al,be}.
  {
    const int t = tid & 31, p = tid >> 5;
    float dq = 0.f, dk = 0.f;
    const float4* qr  = (const float4*)&Qs[t * QSTR];
    const float4* wqr = (const float4*)&Wqs[p * DD];
    const float4* wkr = (const float4*)&Wks[p * DD];
#pragma unroll
    for (int j = 0; j < 16; ++j) {
      float4 qv = qr[j], w0 = wqr[j], w1 = wkr[j];
      dq = fmaf(qv.x, w0.x, dq); dq = fmaf(qv.y, w0.y, dq);
      dq = fmaf(qv.z, w0.z, dq); dq = fmaf(qv.w, w0.w, dq);
      dk = fmaf(qv.x, w1.x, dk); dk = fmaf(qv.y, w1.y, dk);
      dk = fmaf(qv.z, w1.z, dk); dk = fmaf(qv.w, w1.w, dk);
    }
    float ang = fast_tanh(dq) * KPI4;
    float cq = __cosf(ang), sq = __sinf(ang);
    ang = fast_tanh(dk) * KPI4;
    float ck = __cosf(ang), sk = __sinf(ang);
    kts[p * 32 + t] = make_float2(ck, sk);

    // width-32 inclusive scan over t of (ck, sk), per p-segment
    float rc = ck, rs = sk;
#pragma unroll
    for (int d = 1; d < 32; d <<= 1) {
      float tc = __shfl_up(rc, (unsigned)d, 32);
      float ts = __shfl_up(rs, (unsigned)d, 32);
      if (t >= d) { rc += tc; rs += ts; }
    }
    const float* pr = pref + (size_t)((b * PP + p) * NCH + c) * AGG_STRIDE;
    rc += pr[128]; rs += pr[129];
    float den = fmaf(cq, rc, fmaf(sq, rs, EPSV));
    float ws = Wo[p] * __builtin_amdgcn_rcpf(den);
    abt[p * 32 + t] = make_float2(ws * cq, ws * sq);
  }
  __syncthreads();

  char* zbaseH = (char*)Zh;
  char* zbaseL = (char*)Zl;
  f32x4 acc0 = {0, 0, 0, 0}, acc1 = {0, 0, 0, 0};

#pragma unroll
  for (int h = 0; h < 2; ++h) {
    {  // Phase B(h): thread = (i=l, ph=w); p = h*4+w; k_half = w*64+l.
      const int p = h * 4 + w;
      const float* prC = pref + (size_t)((b * PP + p) * NCH + c) * AGG_STRIDE;
      float Ac = prC[l], As = prC[64 + l];
      const int kb = (w * 64 + l) * 2;     // byte offset of this k in a Z row
#pragma unroll 8
      for (int t = 0; t < CC; ++t) {
        float qv = Qs[t * QSTR + l];
        float2 ks = kts[p * 32 + t];
        float2 ab = abt[p * 32 + t];
        Ac = fmaf(ks.x, qv, Ac);
        As = fmaf(ks.y, qv, As);
        float z = fmaf(ab.x, Ac, ab.y * As);
        unsigned u = __float_as_uint(z);
        unsigned r = u + 0x7fffu + ((u >> 16) & 1u);
        const int ad = (t << 9) + (kb ^ (t << 4));   // 5-bit slot swizzle
        *(short*)(zbaseH + ad) = (short)(r >> 16);
        float lo = z - __uint_as_float(r & 0xffff0000u);
        *(short*)(zbaseL + ad) = (short)(__float_as_uint(lo) >> 16);
      }
    }
    __syncthreads();
    // Phase C(h): pure ds_read + MFMA (B-frags already in registers).
#pragma unroll
    for (int kk = 0; kk < 8; ++kk) {
      const int base = kk * 64 + lg * 16;
      const int rb0 = (lm << 9) + (base ^ (lm << 4));
      const int rb1 = ((16 + lm) << 9) + (base ^ ((16 + lm) << 4));
      short8 ah0 = *(const short8*)(zbaseH + rb0);
      short8 al0 = *(const short8*)(zbaseL + rb0);
      short8 ah1 = *(const short8*)(zbaseH + rb1);
      short8 al1 = *(const short8*)(zbaseL + rb1);
      acc0 = __builtin_amdgcn_mfma_f32_16x16x32_bf16(ah0, bhf[kk], acc0, 0, 0, 0);
      acc1 = __builtin_amdgcn_mfma_f32_16x16x32_bf16(ah1, bhf[kk], acc1, 0, 0, 0);
      acc0 = __builtin_amdgcn_mfma_f32_16x16x32_bf16(al0, bhf[kk], acc0, 0, 0, 0);
      acc1 = __builtin_amdgcn_mfma_f32_16x16x32_bf16(al1, bhf[kk], acc1, 0, 0, 0);
      acc0 = __builtin_amdgcn_mfma_f32_16x16x32_bf16(ah0, blf[kk], acc0, 0, 0, 0);
      acc1 = __builtin_amdgcn_mfma_f32_16x16x32_bf16(ah1, blf[kk], acc1, 0, 0, 0);
    }
    if (h == 0) {  // prefetch h=1 B-fragments; latency hides under B(1)
      const unsigned short* ph_ = WvTh + (size_t)(oc + lm) * 512 + 256 + lg * 8;
      const unsigned short* pl_ = WvTl + (size_t)(oc + lm) * 512 + 256 + lg * 8;
#pragma unroll
      for (int kk = 0; kk < 8; ++kk) {
        bhf[kk] = *(const short8*)(ph_ + kk * 32);
        blf[kk] = *(const short8*)(pl_ + kk * 32);
      }
    }
    __syncthreads();
  }

  // Epilogue: C/D layout col=lane&15 (o), row=(lane>>4)*4+reg (t)  [m89]
  {
    float* ob = out + ((size_t)b * TT + (size_t)c * CC + lg * 4) * DD + oc + lm;
#pragma unroll
    for (int r = 0; r < 4; ++r) {
      ob[r * DD] = acc0[r];
      ob[(16 + r) * DD] = acc1[r];
    }
  }
}

extern "C" void kernel_launch(void* const* d_in, const int* in_sizes, int n_in,
                              void* d_out, int out_size, void* d_ws, size_t ws_size,
                              hipStream_t stream) {
  const float* q  = (const float*)d_in[0];
  const float* Wq = (const float*)d_in[1];
  const float* Wk = (const float*)d_in[2];
  const float* Wv = (const float*)d_in[3];
  const float* Wo = (const float*)d_in[4];
  float* out = (float*)d_out;
  float* agg = (float*)d_ws;  // BB*PP*NCH*130 floats = 4,259,840 B
  unsigned short* WvTh = (unsigned short*)(agg + (size_t)BB * PP * NCH * AGG_STRIDE);
  unsigned short* WvTl = WvTh + (size_t)512 * 64;   // +64 KB each

  k_pass1<<<BB * NCH, 256, 0, stream>>>(q, Wk, Wv, agg, WvTh, WvTl);
  k_pass2<<<BB * PP, 576, 0, stream>>>(agg);
  k_pass3<<<BB * NCH, 256, 0, stream>>>(q, Wq, Wk, Wo, agg, WvTh, WvTl, out);
}